// Round 9
// baseline (433.270 us; speedup 1.0000x reference)
//
#include <hip/hip_runtime.h>
#include <hip/hip_cooperative_groups.h>
#include <math.h>

namespace cg = cooperative_groups;

// Problem dims
#define BSZ_ 8
#define LEN_ 8192
#define NC_  256          // scan chunks per sequence
#define CT_  32           // chunk length

typedef __attribute__((ext_vector_type(8))) short bf16x8;
typedef __attribute__((ext_vector_type(4))) float f32x4;
typedef __attribute__((ext_vector_type(4))) unsigned short u16x4;
typedef __attribute__((ext_vector_type(8))) unsigned short u16x8;

// Workspace layout (float offsets).
#define OFF_PRM 0                                   // 128*16 per-p scalars
#define OFF_W1T 2048                                // bf16 [256][128]  (W1^T: [pc][h])
#define OFF_W2T (OFF_W1T + 16384)                   // bf16 [128][256]  (W2^T: [h][pc])
#define OFF_MPW (OFF_W2T + 16384)                   // float2 [8][128][4]: (m21,m22) of M^{4tq+j+1}
#define OFF_SUM (OFF_MPW + 8192)                    // f32 chunk summaries/prefixes [8][256][256][2]
#define OFF_V2  (OFF_SUM + 1048576)                 // ushort [bc][8][256][4] (fallback path only)

__device__ __forceinline__ unsigned short f2bf(float f) {
    unsigned u = __builtin_bit_cast(unsigned, f);
    u += 0x7fffu + ((u >> 16) & 1u);               // round-to-nearest-even
    return (unsigned short)(u >> 16);
}

// cheap round-half-up bf16 (differs from RNE only on exact ties): 2 VALU ops
__device__ __forceinline__ unsigned short f2bf_fast(float f) {
    unsigned u = __builtin_bit_cast(unsigned, f);
    return (unsigned short)((u + 0x8000u) >> 16);
}

__device__ __forceinline__ float bf2f(unsigned short u) {
    return __builtin_bit_cast(float, (unsigned)u << 16);
}

// ---------------------------------------------------------------------------
// Setup: weight conversion + per-p scalars + packed M-power table (k=1..32)
// + T=M^32, U=M^512.  grid = 128 x 256
// ---------------------------------------------------------------------------
__global__ __launch_bounds__(256) void k_setup(const float* __restrict__ A_diag,
                                               const float* __restrict__ G_diag,
                                               const float* __restrict__ dt,
                                               const float* __restrict__ B,
                                               const float* __restrict__ C,
                                               float* __restrict__ ws)
{
    int i = blockIdx.x * 256 + threadIdx.x;        // 0..32767
    {
        int pc = i >> 7, h = i & 127;
        int p = pc >> 1, cc = pc & 1;
        float dts = 1.f / (1.f + expf(-dt[p]));
        float G = fmaxf(G_diag[p], 0.f);
        float c1 = dts / (1.f + dts * G);
        ((unsigned short*)(ws + OFF_W1T))[i] = f2bf(c1 * B[p * 256 + h * 2 + cc]);
    }
    {
        float v = C[i];
        ((unsigned short*)(ws + OFF_W2T))[i] = f2bf((i & 1) ? -v : v);
    }
    if (i < 4096) {
        int k = (i >> 7) + 1;                      // 1..32
        int p = i & 127;
        float dtv = dt[p];
        float dts = 1.f / (1.f + expf(-dtv));
        float A   = fmaxf(A_diag[p], 0.f);
        float G   = fmaxf(G_diag[p], 0.f);
        float dt2 = fmaxf(dts * dts, 1e-6f);
        float s   = sqrtf(1.f + dts * G);
        float A_low  = (2.f + dts * G - 2.f * s) / dt2;
        float A_high = (2.f + dts * G + 2.f * s) / dt2;
        float Af = A_low + fmaxf(A - A_low, 0.f) - fmaxf(A - A_high, 0.f);
        float S   = 1.f + dts * G;
        float M11 = 1.f / S;
        float M12 = -(dts / S) * Af;
        float M21 = dts / S;
        float M22 = 1.f - (dts * dts / S) * Af;

        float r11 = 1.f, r12 = 0.f, r21 = 0.f, r22 = 1.f;
        float b11 = M11, b12 = M12, b21 = M21, b22 = M22;
        int kk = k;
#pragma unroll
        for (int it = 0; it < 6; ++it) {
            if (kk & 1) {
                float t11 = b11 * r11 + b12 * r21;
                float t12 = b11 * r12 + b12 * r22;
                float t21 = b21 * r11 + b22 * r21;
                float t22 = b21 * r12 + b22 * r22;
                r11 = t11; r12 = t12; r21 = t21; r22 = t22;
            }
            float s11 = b11 * b11 + b12 * b21;
            float s12 = b11 * b12 + b12 * b22;
            float s21 = b21 * b11 + b22 * b21;
            float s22 = b21 * b12 + b22 * b22;
            b11 = s11; b12 = s12; b21 = s21; b22 = s22;
            kk >>= 1;
        }
        {
            int tq = (k - 1) >> 2, j = (k - 1) & 3;
            ((float2*)(ws + OFF_MPW))[((size_t)tq * 128 + p) * 4 + j] =
                make_float2(r21, r22);
        }
        float* prm = ws + OFF_PRM + p * 16;
        if (k == 1) {
            prm[0] = M11; prm[1] = M12; prm[2] = M21; prm[3] = M22; prm[4] = dts;
        }
        if (k == 32) {                              // T = M^32
            prm[5] = r11; prm[6] = r12; prm[7] = r21; prm[8] = r22;
            float u11 = r11, u12 = r12, u21 = r21, u22 = r22;
#pragma unroll
            for (int it = 0; it < 4; ++it) {        // U = M^512
                float s11 = u11 * u11 + u12 * u21;
                float s12 = u11 * u12 + u12 * u22;
                float s21 = u21 * u11 + u22 * u21;
                float s22 = u21 * u12 + u22 * u22;
                u11 = s11; u12 = s12; u21 = s21; u22 = s22;
            }
            prm[9] = u11; prm[10] = u12; prm[11] = u21; prm[12] = u22;
        }
    }
}

// ---------------------------------------------------------------------------
// Shared device pieces
// ---------------------------------------------------------------------------
__device__ __forceinline__ void stage_x32(const float* __restrict__ X, size_t row0,
                                          int tid, unsigned short (*xs)[136])
{
    int r = tid >> 4, cl = (tid & 15) * 8;
#pragma unroll
    for (int i = 0; i < 2; ++i) {
        int rr = r + i * 16;
        const float* src = X + (row0 + rr) * 128 + cl;
        float4 v0 = *(const float4*)src;
        float4 v1 = *(const float4*)(src + 4);
        u16x8 pk;
        pk[0] = f2bf_fast(v0.x); pk[1] = f2bf_fast(v0.y);
        pk[2] = f2bf_fast(v0.z); pk[3] = f2bf_fast(v0.w);
        pk[4] = f2bf_fast(v1.x); pk[5] = f2bf_fast(v1.y);
        pk[6] = f2bf_fast(v1.z); pk[7] = f2bf_fast(v1.w);
        *(u16x8*)&xs[rr][cl] = pk;
    }
}

__device__ __forceinline__ void gemm1_acc32(const unsigned short (*xs)[136],
                                            const unsigned short* __restrict__ W1T,
                                            int wv, int lane, f32x4 acc[2][4])
{
    int l15 = lane & 15, quad = lane >> 4;
    int nbase = wv * 64;
#pragma unroll
    for (int kk = 0; kk < 4; ++kk) {
        int k0 = kk * 32 + quad * 8;
        bf16x8 af[2], bg[4];
#pragma unroll
        for (int mi = 0; mi < 2; ++mi) af[mi] = *(const bf16x8*)&xs[mi * 16 + l15][k0];
#pragma unroll
        for (int nj = 0; nj < 4; ++nj)
            bg[nj] = *(const bf16x8*)(W1T + (size_t)(nbase + nj * 16 + l15) * 128 + k0);
#pragma unroll
        for (int mi = 0; mi < 2; ++mi)
#pragma unroll
            for (int nj = 0; nj < 4; ++nj)
                acc[mi][nj] = __builtin_amdgcn_mfma_f32_16x16x32_bf16(af[mi], bg[nj], acc[mi][nj], 0, 0, 0);
    }
}

// GEMM2 (32x128x256) + epilogue for one 32-row sub-chunk
__device__ __forceinline__ void gemm2_epi(const unsigned short (*ysb)[264],
                                          const unsigned short* __restrict__ W2T,
                                          const float* __restrict__ X,
                                          const float* __restrict__ Dv,
                                          float* __restrict__ out,
                                          size_t rowbase, int wv, int lane)
{
    int l15 = lane & 15, quad = lane >> 4;
    int mrow = (wv & 1) * 16, ncol = (wv >> 1) * 64;
    f32x4 a2[4] = {};
#pragma unroll
    for (int kk = 0; kk < 8; ++kk) {
        int k0 = kk * 32 + quad * 8;
        bf16x8 af = *(const bf16x8*)&ysb[mrow + l15][k0];
        bf16x8 bg[4];
#pragma unroll
        for (int nj = 0; nj < 4; ++nj)
            bg[nj] = *(const bf16x8*)(W2T + (size_t)(ncol + nj * 16 + l15) * 256 + k0);
#pragma unroll
        for (int nj = 0; nj < 4; ++nj)
            a2[nj] = __builtin_amdgcn_mfma_f32_16x16x32_bf16(af, bg[nj], a2[nj], 0, 0, 0);
    }
#pragma unroll
    for (int nj = 0; nj < 4; ++nj) {
        int col = ncol + nj * 16 + l15;
        float d = Dv[col];
#pragma unroll
        for (int r = 0; r < 4; ++r) {
            size_t gr = rowbase + mrow + quad * 4 + r;
            float xv = X[gr * 128 + col];
            out[gr * 128 + col] = fmaf(d, xv, a2[nj][r]);
        }
    }
}

// ---------------------------------------------------------------------------
// COOPERATIVE single kernel: grid 1024 (4 blk/CU co-resident), each block
// owns two 32-chunks.  GEMM1 accumulators persist in VGPRs across TWO
// grid.sync()s -> no V2 round-trip, no recompute, no extra launches.
// LDS: region1 17408 (xs | 4 wave-local fw slices) + ysb 16896 + sums 2048
//   = 36.4 KB -> 4 blk/CU.  __launch_bounds__(256,4) caps VGPR at 128.
// ---------------------------------------------------------------------------
__global__ __launch_bounds__(256, 4) void k_coop(const float* __restrict__ X,
                                                 const float* __restrict__ Dv,
                                                 float* __restrict__ ws,
                                                 float* __restrict__ out)
{
    __shared__ __align__(16) char sm1[17408];                 // xs | fw slices
    __shared__ __align__(16) unsigned short ysb[32][264];
    __shared__ float2 sums[16][16];

    cg::grid_group grid = cg::this_grid();

    int tid = threadIdx.x;
    int bid = blockIdx.x;                          // 0..1023
    int b = bid >> 7, cb = bid & 127;
    size_t row0 = (size_t)b * LEN_ + (size_t)cb * 64;
    int wv = tid >> 6, lane = tid & 63;
    int l15 = lane & 15, quad = lane >> 4;

    unsigned short (*xs)[136] = (unsigned short (*)[136])sm1;
    float (*fw)[68] = (float (*)[68])(sm1 + wv * 4352);       // wave-local slice

    const float* prm = ws + OFF_PRM + (tid >> 1) * 16;
    float M11 = prm[0], M12 = prm[1], dts = prm[4];

    f32x4 acc0[2][4] = {}, acc1[2][4] = {};

#define SCAN_SUM(ACC, S1, S2)                                              \
    {                                                                      \
        float h1 = 0.f, h2 = 0.f;                                          \
        _Pragma("unroll") for (int half = 0; half < 2; ++half) {           \
            _Pragma("unroll") for (int nj = 0; nj < 4; ++nj)               \
                _Pragma("unroll") for (int r = 0; r < 4; ++r)              \
                    fw[quad * 4 + r][nj * 16 + l15] = ACC[half][nj][r];    \
            _Pragma("unroll") for (int t = 0; t < 16; ++t) {               \
                float u = fw[t][lane];                                     \
                float n1 = fmaf(M11, h1, fmaf(M12, h2, u));                \
                float n2 = fmaf(dts, n1, h2);                              \
                h1 = n1; h2 = n2;                                          \
            }                                                              \
        }                                                                  \
        S1 = h1; S2 = h2;                                                  \
    }

    // ---- phase 1: GEMM1 both sub-chunks + local scans -> summaries ----
    stage_x32(X, row0, tid, xs);
    __syncthreads();
    gemm1_acc32(xs, (const unsigned short*)(ws + OFF_W1T), wv, lane, acc0);
    __syncthreads();            // xs dead; fw may overwrite
    float s01, s02, s11, s12;
    SCAN_SUM(acc0, s01, s02);
    __syncthreads();            // all waves done with fw; restage xs
    stage_x32(X, row0 + 32, tid, xs);
    __syncthreads();
    gemm1_acc32(xs, (const unsigned short*)(ws + OFF_W1T), wv, lane, acc1);
    __syncthreads();
    SCAN_SUM(acc1, s11, s12);
    *(float2*)(ws + OFF_SUM + (((size_t)b * NC_ + 2 * cb) * 256 + tid) * 2) =
        make_float2(s01, s02);
    *(float2*)(ws + OFF_SUM + (((size_t)b * NC_ + 2 * cb + 1) * 256 + tid) * 2) =
        make_float2(s11, s12);

    grid.sync();

    // ---- scan2 phase (blocks 0..127): two-level combine, re-read variant ----
    if (bid < 128) {
        int b2 = bid >> 4, chb = (bid & 15) * 16;
        int chl = tid & 15, seg = tid >> 4;
        int ch = chb + chl;
        const float* pr2 = ws + OFF_PRM + (ch >> 1) * 16;
        float T11 = pr2[5], T12 = pr2[6], T21 = pr2[7], T22 = pr2[8];
        float U11 = pr2[9], U12 = pr2[10], U21 = pr2[11], U22 = pr2[12];
        float* base = ws + OFF_SUM + (size_t)b2 * (NC_ * 512) + ch * 2;

        float s1 = 0.f, s2 = 0.f;
#pragma unroll
        for (int j = 0; j < 16; ++j) {
            float2 l = *(const float2*)(base + (size_t)(seg * 16 + j) * 512);
            float n1 = fmaf(T11, s1, fmaf(T12, s2, l.x));
            float n2 = fmaf(T21, s1, fmaf(T22, s2, l.y));
            s1 = n1; s2 = n2;
        }
        sums[chl][seg] = make_float2(s1, s2);
        __syncthreads();
        if (tid < 16) {
            float e1 = 0.f, e2 = 0.f;
#pragma unroll
            for (int k = 0; k < 16; ++k) {
                float2 t = sums[tid][k];
                sums[tid][k] = make_float2(e1, e2);
                float n1 = fmaf(U11, e1, fmaf(U12, e2, t.x));
                float n2 = fmaf(U21, e1, fmaf(U22, e2, t.y));
                e1 = n1; e2 = n2;
            }
        }
        __syncthreads();
        float2 E = sums[chl][seg];
        float e1 = E.x, e2 = E.y;
#pragma unroll
        for (int j = 0; j < 16; ++j) {
            float2 l = *(const float2*)(base + (size_t)(seg * 16 + j) * 512);
            *(float2*)(base + (size_t)(seg * 16 + j) * 512) = make_float2(e1, e2);
            float n1 = fmaf(T11, e1, fmaf(T12, e2, l.x));
            float n2 = fmaf(T21, e1, fmaf(T22, e2, l.y));
            e1 = n1; e2 = n2;
        }
    }

    grid.sync();

    // ---- phase 3: rescan from regs + prefix-apply -> ysb -> GEMM2+epi ----
    const float2* MPW = (const float2*)(ws + OFF_MPW);
    int p = tid >> 1;
    const unsigned short* W2T = (const unsigned short*)(ws + OFF_W2T);

#define PHASE3(ACC, CIDX)                                                  \
    {                                                                      \
        float2 Cp = *(const float2*)(ws + OFF_SUM +                        \
                     (((size_t)b * NC_ + (CIDX)) * 256 + tid) * 2);        \
        float h1 = 0.f, h2 = 0.f;                                          \
        _Pragma("unroll") for (int half = 0; half < 2; ++half) {           \
            _Pragma("unroll") for (int nj = 0; nj < 4; ++nj)               \
                _Pragma("unroll") for (int r = 0; r < 4; ++r)              \
                    fw[quad * 4 + r][nj * 16 + l15] = ACC[half][nj][r];    \
            _Pragma("unroll") for (int t = 0; t < 16; ++t) {               \
                int tt = half * 16 + t;                                    \
                float u = fw[t][lane];                                     \
                float n1 = fmaf(M11, h1, fmaf(M12, h2, u));                \
                float n2 = fmaf(dts, n1, h2);                              \
                h1 = n1; h2 = n2;                                          \
                float2 m = MPW[((size_t)(tt >> 2) * 128 + p) * 4 + (tt & 3)]; \
                float y = fmaf(m.x, Cp.x, fmaf(m.y, Cp.y, n2));            \
                ysb[tt][tid] = f2bf_fast(y);                               \
            }                                                              \
        }                                                                  \
    }

    PHASE3(acc0, 2 * cb);
    __syncthreads();
    gemm2_epi(ysb, W2T, X, Dv, out, row0, wv, lane);
    __syncthreads();
    PHASE3(acc1, 2 * cb + 1);
    __syncthreads();
    gemm2_epi(ysb, W2T, X, Dv, out, row0 + 32, wv, lane);
#undef SCAN_SUM
#undef PHASE3
}

// ---------------------------------------------------------------------------
// FALLBACK path (round-8 kernels, verified): used if cooperative launch fails
// ---------------------------------------------------------------------------
__global__ __launch_bounds__(256) void k_fuse1(const float* __restrict__ X,
                                               float* __restrict__ ws)
{
    __shared__ __align__(16) char smem[16 * 260 * 4];
    unsigned short (*xs)[136] = (unsigned short (*)[136])smem;
    float (*fl)[260] = (float (*)[260])smem;

    int tid = threadIdx.x;
    int bc = blockIdx.x;
    int b = bc >> 8, c = bc & 255;
    size_t row0 = (size_t)b * LEN_ + (size_t)c * CT_;

    stage_x32(X, row0, tid, xs);
    __syncthreads();

    int wv = tid >> 6, lane = tid & 63;
    int l15 = lane & 15, quad = lane >> 4, nbase = wv * 64;
    f32x4 acc[2][4] = {};
    gemm1_acc32(xs, (const unsigned short*)(ws + OFF_W1T), wv, lane, acc);
    __syncthreads();

    const float* prm = ws + OFF_PRM + (tid >> 1) * 16;
    float M11 = prm[0], M12 = prm[1], dts = prm[4];
    u16x4* V2q = (u16x4*)(ws + OFF_V2) + (size_t)bc * 2048;
    float h1 = 0.f, h2 = 0.f;

#pragma unroll
    for (int half = 0; half < 2; ++half) {
#pragma unroll
        for (int nj = 0; nj < 4; ++nj)
#pragma unroll
            for (int r = 0; r < 4; ++r)
                fl[quad * 4 + r][nbase + nj * 16 + l15] = acc[half][nj][r];
        __syncthreads();
#pragma unroll
        for (int g = 0; g < 4; ++g) {
            u16x4 pk;
#pragma unroll
            for (int i = 0; i < 4; ++i) {
                float u = fl[g * 4 + i][tid];
                float n1 = fmaf(M11, h1, fmaf(M12, h2, u));
                float n2 = fmaf(dts, n1, h2);
                h1 = n1; h2 = n2;
                pk[i] = f2bf_fast(h2);
            }
            V2q[(half * 4 + g) * 256 + tid] = pk;
        }
        __syncthreads();
    }
    *(float2*)(ws + OFF_SUM + ((size_t)bc * 256 + tid) * 2) = make_float2(h1, h2);
}

__global__ __launch_bounds__(256) void k_scan2(float* __restrict__ ws)
{
    __shared__ float2 sums[16][16];
    int blk = blockIdx.x;
    int b = blk >> 4, chb = (blk & 15) * 16;
    int tid = threadIdx.x;
    int chl = tid & 15, seg = tid >> 4;
    int ch = chb + chl;
    const float* prm = ws + OFF_PRM + (ch >> 1) * 16;
    float T11 = prm[5], T12 = prm[6], T21 = prm[7], T22 = prm[8];
    float U11 = prm[9], U12 = prm[10], U21 = prm[11], U22 = prm[12];
    float* base = ws + OFF_SUM + (size_t)b * (NC_ * 512) + ch * 2;

    float l1[16], l2[16];
    float s1 = 0.f, s2 = 0.f;
#pragma unroll
    for (int j = 0; j < 16; ++j) {
        float2 l = *(const float2*)(base + (size_t)(seg * 16 + j) * 512);
        l1[j] = l.x; l2[j] = l.y;
        float n1 = fmaf(T11, s1, fmaf(T12, s2, l.x));
        float n2 = fmaf(T21, s1, fmaf(T22, s2, l.y));
        s1 = n1; s2 = n2;
    }
    sums[chl][seg] = make_float2(s1, s2);
    __syncthreads();
    if (tid < 16) {
        float e1 = 0.f, e2 = 0.f;
#pragma unroll
        for (int k = 0; k < 16; ++k) {
            float2 t = sums[tid][k];
            sums[tid][k] = make_float2(e1, e2);
            float n1 = fmaf(U11, e1, fmaf(U12, e2, t.x));
            float n2 = fmaf(U21, e1, fmaf(U22, e2, t.y));
            e1 = n1; e2 = n2;
        }
    }
    __syncthreads();
    float2 E = sums[chl][seg];
    float e1 = E.x, e2 = E.y;
#pragma unroll
    for (int j = 0; j < 16; ++j) {
        *(float2*)(base + (size_t)(seg * 16 + j) * 512) = make_float2(e1, e2);
        float n1 = fmaf(T11, e1, fmaf(T12, e2, l1[j]));
        float n2 = fmaf(T21, e1, fmaf(T22, e2, l2[j]));
        e1 = n1; e2 = n2;
    }
}

__global__ __launch_bounds__(256) void k_fuse2(const float* __restrict__ X,
                                               const float* __restrict__ Dv,
                                               float* __restrict__ ws,
                                               float* __restrict__ out)
{
    __shared__ __align__(16) unsigned short ysb[32][264];

    int tid = threadIdx.x;
    int bc = blockIdx.x;
    int b = bc >> 8, c = bc & 255;
    size_t row0 = (size_t)b * LEN_ + (size_t)c * CT_;

    {
        int q = tid & 127;
        int tseg = tid >> 7;
        float4 Cp = *(const float4*)(ws + OFF_SUM + ((size_t)bc * 256 + 2 * q) * 2);
        const unsigned short* V2b = (const unsigned short*)(ws + OFF_V2) +
                                    (size_t)bc * 8192;
        const float2* MPW = (const float2*)(ws + OFF_MPW);
#pragma unroll
        for (int g = 0; g < 4; ++g) {
            int tq = tseg * 4 + g;
            u16x8 v = *(const u16x8*)(V2b + (size_t)tq * 1024 + 8 * q);
            const float2* MP = MPW + ((size_t)tq * 128 + q) * 4;
            float4 mA = *(const float4*)MP;
            float4 mB = *(const float4*)(MP + 2);
            int t0 = tq * 4;
            float y0, y1;
            y0 = fmaf(mA.x, Cp.x, fmaf(mA.y, Cp.y, bf2f(v[0])));
            y1 = fmaf(mA.x, Cp.z, fmaf(mA.y, Cp.w, bf2f(v[4])));
            *(ushort2*)&ysb[t0 + 0][2 * q] = make_ushort2(f2bf_fast(y0), f2bf_fast(y1));
            y0 = fmaf(mA.z, Cp.x, fmaf(mA.w, Cp.y, bf2f(v[1])));
            y1 = fmaf(mA.z, Cp.z, fmaf(mA.w, Cp.w, bf2f(v[5])));
            *(ushort2*)&ysb[t0 + 1][2 * q] = make_ushort2(f2bf_fast(y0), f2bf_fast(y1));
            y0 = fmaf(mB.x, Cp.x, fmaf(mB.y, Cp.y, bf2f(v[2])));
            y1 = fmaf(mB.x, Cp.z, fmaf(mB.y, Cp.w, bf2f(v[6])));
            *(ushort2*)&ysb[t0 + 2][2 * q] = make_ushort2(f2bf_fast(y0), f2bf_fast(y1));
            y0 = fmaf(mB.z, Cp.x, fmaf(mB.w, Cp.y, bf2f(v[3])));
            y1 = fmaf(mB.z, Cp.z, fmaf(mB.w, Cp.w, bf2f(v[7])));
            *(ushort2*)&ysb[t0 + 3][2 * q] = make_ushort2(f2bf_fast(y0), f2bf_fast(y1));
        }
    }
    __syncthreads();

    int wv = tid >> 6, lane = tid & 63;
    gemm2_epi(ysb, (const unsigned short*)(ws + OFF_W2T), X, Dv, out, row0, wv, lane);
}

// ---------------------------------------------------------------------------
extern "C" void kernel_launch(void* const* d_in, const int* in_sizes, int n_in,
                              void* d_out, int out_size, void* d_ws, size_t ws_size,
                              hipStream_t stream) {
    const float* x      = (const float*)d_in[0];
    const float* A_diag = (const float*)d_in[1];
    const float* G_diag = (const float*)d_in[2];
    const float* dt     = (const float*)d_in[3];
    const float* B      = (const float*)d_in[4];
    const float* C      = (const float*)d_in[5];
    const float* Dv     = (const float*)d_in[6];
    float* out = (float*)d_out;
    float* ws  = (float*)d_ws;

    k_setup<<<128, 256, 0, stream>>>(A_diag, G_diag, dt, B, C, ws);

    const float* Xa = x; const float* Da = Dv; float* wsa = ws; float* outa = out;
    void* kargs[] = { (void*)&Xa, (void*)&Da, (void*)&wsa, (void*)&outa };
    hipError_t err = hipLaunchCooperativeKernel((void*)k_coop, dim3(1024), dim3(256),
                                                kargs, 0, stream);
    if (err != hipSuccess) {
        (void)hipGetLastError();                   // clear error state
        k_fuse1<<<BSZ_ * NC_, 256, 0, stream>>>(x, ws);
        k_scan2<<<128, 256, 0, stream>>>(ws);
        k_fuse2<<<BSZ_ * NC_, 256, 0, stream>>>(x, Dv, ws, out);
    }
}

// Round 10
// 279.913 us; speedup vs baseline: 1.5479x; 1.5479x over previous
//
#include <hip/hip_runtime.h>
#include <math.h>

// Problem dims
#define BSZ_ 8
#define LEN_ 8192
#define NC_  128          // scan chunks per sequence
#define CT_  64           // chunk length

typedef __attribute__((ext_vector_type(8))) short bf16x8;
typedef __attribute__((ext_vector_type(4))) float f32x4;
typedef __attribute__((ext_vector_type(4))) unsigned short u16x4;
typedef __attribute__((ext_vector_type(8))) unsigned short u16x8;
typedef unsigned long long ulong64;

// Workspace layout (float offsets).
#define OFF_PRM 0                                   // 128*16 per-p scalars
#define OFF_W1T 2048                                // bf16 [256][128]  (W1^T: [pc][h])
#define OFF_W2T (OFF_W1T + 16384)                   // bf16 [128][256]  (W2^T: [h][pc])
#define OFF_MPW (OFF_W2T + 16384)                   // float2 [16][128][4]: (m21,m22) of M^{4tq+j+1}
#define OFF_SUM (OFF_MPW + 16384)                   // float2 [8][128][256] summaries -> prefixes
#define OFF_V2  (OFF_SUM + 524288)                  // u16x4 [1024][16][256]: v2 bf16, 4-t packed
#define OFF_CNT (OFF_V2 + 8388608)                  // unsigned [8]: per-batch done counters

__device__ __forceinline__ unsigned short f2bf(float f) {
    unsigned u = __builtin_bit_cast(unsigned, f);
    u += 0x7fffu + ((u >> 16) & 1u);               // round-to-nearest-even
    return (unsigned short)(u >> 16);
}

// cheap round-half-up bf16 (differs from RNE only on exact ties): 2 VALU ops
__device__ __forceinline__ unsigned short f2bf_fast(float f) {
    unsigned u = __builtin_bit_cast(unsigned, f);
    return (unsigned short)((u + 0x8000u) >> 16);
}

__device__ __forceinline__ float bf2f(unsigned short u) {
    return __builtin_bit_cast(float, (unsigned)u << 16);
}

// 8-byte agent-scope atomics (value-carrying, R5-proven primitive)
__device__ __forceinline__ void pub8(ulong64* a, float x, float y) {
    float2 v = make_float2(x, y);
    __hip_atomic_store(a, __builtin_bit_cast(ulong64, v),
                       __ATOMIC_RELAXED, __HIP_MEMORY_SCOPE_AGENT);
}
__device__ __forceinline__ float2 rd8(const ulong64* a) {
    ulong64 v = __hip_atomic_load((ulong64*)a, __ATOMIC_RELAXED,
                                  __HIP_MEMORY_SCOPE_AGENT);
    return __builtin_bit_cast(float2, v);
}

// ---------------------------------------------------------------------------
// Setup: weight conversion + per-p scalars + packed M-power table + T=M^64,
// U=M^1024 + counter reset.  grid = 128 x 256
// ---------------------------------------------------------------------------
__global__ __launch_bounds__(256) void k_setup(const float* __restrict__ A_diag,
                                               const float* __restrict__ G_diag,
                                               const float* __restrict__ dt,
                                               const float* __restrict__ B,
                                               const float* __restrict__ C,
                                               float* __restrict__ ws)
{
    int i = blockIdx.x * 256 + threadIdx.x;        // 0..32767
    // W1T[pc][h] = c1[p] * B[p,h,c]
    {
        int pc = i >> 7, h = i & 127;
        int p = pc >> 1, cc = pc & 1;
        float dts = 1.f / (1.f + expf(-dt[p]));
        float G = fmaxf(G_diag[p], 0.f);
        float c1 = dts / (1.f + dts * G);
        ((unsigned short*)(ws + OFF_W1T))[i] = f2bf(c1 * B[p * 256 + h * 2 + cc]);
    }
    // W2T[h][pc] = +Cr / -Ci ; C layout is exactly linear in i
    {
        float v = C[i];
        ((unsigned short*)(ws + OFF_W2T))[i] = f2bf((i & 1) ? -v : v);
    }
    if (i < 8) ((unsigned*)(ws + OFF_CNT))[i] = 0u;

    // M-power table, fully parallel: threads 0..8191 -> (k = 1..64, p = 0..127)
    if (i < 8192) {
        int k = (i >> 7) + 1;                      // 1..64
        int p = i & 127;
        float dtv = dt[p];
        float dts = 1.f / (1.f + expf(-dtv));
        float A   = fmaxf(A_diag[p], 0.f);
        float G   = fmaxf(G_diag[p], 0.f);
        float dt2 = fmaxf(dts * dts, 1e-6f);
        float s   = sqrtf(1.f + dts * G);
        float A_low  = (2.f + dts * G - 2.f * s) / dt2;
        float A_high = (2.f + dts * G + 2.f * s) / dt2;
        float Af = A_low + fmaxf(A - A_low, 0.f) - fmaxf(A - A_high, 0.f);
        float S   = 1.f + dts * G;
        float M11 = 1.f / S;
        float M12 = -(dts / S) * Af;
        float M21 = dts / S;
        float M22 = 1.f - (dts * dts / S) * Af;

        // R = M^k via binary exponentiation (powers of M commute)
        float r11 = 1.f, r12 = 0.f, r21 = 0.f, r22 = 1.f;
        float b11 = M11, b12 = M12, b21 = M21, b22 = M22;
        int kk = k;
#pragma unroll
        for (int it = 0; it < 7; ++it) {
            if (kk & 1) {
                float t11 = b11 * r11 + b12 * r21;
                float t12 = b11 * r12 + b12 * r22;
                float t21 = b21 * r11 + b22 * r21;
                float t22 = b21 * r12 + b22 * r22;
                r11 = t11; r12 = t12; r21 = t21; r22 = t22;
            }
            float s11 = b11 * b11 + b12 * b21;
            float s12 = b11 * b12 + b12 * b22;
            float s21 = b21 * b11 + b22 * b21;
            float s22 = b21 * b12 + b22 * b22;
            b11 = s11; b12 = s12; b21 = s21; b22 = s22;
            kk >>= 1;
        }
        // packed table: MPW[tq][p][j] = (m21,m22) of M^{4tq+j+1}
        {
            int tq = (k - 1) >> 2, j = (k - 1) & 3;
            ((float2*)(ws + OFF_MPW))[((size_t)tq * 128 + p) * 4 + j] =
                make_float2(r21, r22);
        }

        float* prm = ws + OFF_PRM + p * 16;
        if (k == 1) {
            prm[0] = M11; prm[1] = M12; prm[2] = M21; prm[3] = M22; prm[4] = dts;
        }
        if (k == 64) {                              // T = M^64 for scan2
            prm[5] = r11; prm[6] = r12; prm[7] = r21; prm[8] = r22;
            // U = T^16 = M^1024 (segment step): 4 more squarings
            float u11 = r11, u12 = r12, u21 = r21, u22 = r22;
#pragma unroll
            for (int it = 0; it < 4; ++it) {
                float s11 = u11 * u11 + u12 * u21;
                float s12 = u11 * u12 + u12 * u22;
                float s21 = u21 * u11 + u22 * u21;
                float s22 = u21 * u12 + u22 * u22;
                u11 = s11; u12 = s12; u21 = s21; u22 = s22;
            }
            prm[9] = u11; prm[10] = u12; prm[11] = u21; prm[12] = u22;
        }
    }
}

// ---------------------------------------------------------------------------
// Shared device pieces
// ---------------------------------------------------------------------------
__device__ __forceinline__ void stage_x(const float* __restrict__ X, size_t row0,
                                        int tid, unsigned short (*xs)[136])
{
    int r = tid >> 4, cl = (tid & 15) * 8;
#pragma unroll
    for (int i = 0; i < 4; ++i) {
        int rr = r + i * 16;
        const float* src = X + (row0 + rr) * 128 + cl;
        float4 v0 = *(const float4*)src;
        float4 v1 = *(const float4*)(src + 4);
        u16x8 pk;
        pk[0] = f2bf_fast(v0.x); pk[1] = f2bf_fast(v0.y);
        pk[2] = f2bf_fast(v0.z); pk[3] = f2bf_fast(v0.w);
        pk[4] = f2bf_fast(v1.x); pk[5] = f2bf_fast(v1.y);
        pk[6] = f2bf_fast(v1.z); pk[7] = f2bf_fast(v1.w);
        *(u16x8*)&xs[rr][cl] = pk;                 // one 16B LDS store
    }
}

// GEMM1 64x256x128: A = xs (LDS), B-frags straight from global W1T (L2-hot)
__device__ __forceinline__ void gemm1_acc(const unsigned short (*xs)[136],
                                          const unsigned short* __restrict__ W1T,
                                          int wv, int lane, f32x4 acc[4][4])
{
    int l15 = lane & 15, quad = lane >> 4;
    int nbase = wv * 64;
#pragma unroll
    for (int kk = 0; kk < 4; ++kk) {
        int k0 = kk * 32 + quad * 8;
        bf16x8 af[4], bg[4];
#pragma unroll
        for (int mi = 0; mi < 4; ++mi) af[mi] = *(const bf16x8*)&xs[mi * 16 + l15][k0];
#pragma unroll
        for (int nj = 0; nj < 4; ++nj)
            bg[nj] = *(const bf16x8*)(W1T + (size_t)(nbase + nj * 16 + l15) * 128 + k0);
#pragma unroll
        for (int mi = 0; mi < 4; ++mi)
#pragma unroll
            for (int nj = 0; nj < 4; ++nj)
                acc[mi][nj] = __builtin_amdgcn_mfma_f32_16x16x32_bf16(af[mi], bg[nj], acc[mi][nj], 0, 0, 0);
    }
}

// ---------------------------------------------------------------------------
// Fused 1: GEMM1 + chunk-local scan (R7-proven) + MERGED scan2: the last
// block per batch (non-blocking atomic count, never spins) performs the
// two-level prefix combine inline.  SUM published via 8B agent-scope atomics.
// LDS = 33.3 KB -> 4 blk/CU.  grid = 1024 x 256
// ---------------------------------------------------------------------------
__global__ __launch_bounds__(256) void k_fuse1(const float* __restrict__ X,
                                               float* __restrict__ ws)
{
    __shared__ __align__(16) char smem[32 * 260 * 4];
    __shared__ int lastdone;
    unsigned short (*xs)[136] = (unsigned short (*)[136])smem;  // alias (dead after GEMM1)
    float (*fl)[260] = (float (*)[260])smem;                    // fp32 half-tile (32 rows)

    int tid = threadIdx.x;
    int bc = blockIdx.x;
    int b = bc >> 7, c = bc & 127;
    size_t row0 = (size_t)b * LEN_ + (size_t)c * CT_;

    stage_x(X, row0, tid, xs);
    __syncthreads();

    int wv = tid >> 6, lane = tid & 63;
    int l15 = lane & 15, quad = lane >> 4, nbase = wv * 64;
    f32x4 acc[4][4] = {};
    gemm1_acc(xs, (const unsigned short*)(ws + OFF_W1T), wv, lane, acc);
    __syncthreads();            // xs fully consumed; fl may now overwrite it

    const float* prm = ws + OFF_PRM + (tid >> 1) * 16;
    float M11 = prm[0], M12 = prm[1], dts = prm[4];
    u16x4* V2q = (u16x4*)(ws + OFF_V2) + (size_t)bc * 4096;  // [16][256] u16x4
    float h1 = 0.f, h2 = 0.f;

#pragma unroll
    for (int half = 0; half < 2; ++half) {
        // stage rows [half*32, half*32+32) of acc into fl
#pragma unroll
        for (int mi = 0; mi < 2; ++mi)
#pragma unroll
            for (int nj = 0; nj < 4; ++nj)
#pragma unroll
                for (int r = 0; r < 4; ++r)
                    fl[mi * 16 + quad * 4 + r][nbase + nj * 16 + l15] =
                        acc[half * 2 + mi][nj][r];
        __syncthreads();
        // scan 32 rows = 8 groups of 4; pack 4 bf16 -> one 8B store
#pragma unroll
        for (int g = 0; g < 8; ++g) {
            u16x4 pk;
#pragma unroll
            for (int i = 0; i < 4; ++i) {
                float u = fl[g * 4 + i][tid];
                float n1 = fmaf(M11, h1, fmaf(M12, h2, u));
                float n2 = fmaf(dts, n1, h2);      // == M21*h1 + M22*h2 + dts*u
                h1 = n1; h2 = n2;
                pk[i] = f2bf_fast(h2);
            }
            V2q[(half * 8 + g) * 256 + tid] = pk;
        }
        __syncthreads();        // fl reads done before next half overwrites
    }

    // publish chunk summary (8B agent atomic) and count completion
    ulong64* SUM = (ulong64*)(ws + OFF_SUM);
    pub8(&SUM[(size_t)bc * 256 + tid], h1, h2);
    __threadfence();
    if (tid == 0)
        lastdone = (atomicAdd(&((unsigned*)(ws + OFF_CNT))[b], 1u) == NC_ - 1);
    __syncthreads();
    if (!lastdone) return;

    // ---- last block of batch b: inline scan2 (two-level combine) ----
    __threadfence();                               // acquire others' summaries
    float2 (*sums)[8] = (float2 (*)[8])smem;       // alias (fl dead)
    int chl = tid & 31, seg = tid >> 5;            // coalesced mapping
    ulong64* base0 = SUM + (size_t)b * (NC_ * 256);
#pragma unroll 1
    for (int cg = 0; cg < 8; ++cg) {
        int ch = cg * 32 + chl;
        const float* pr2 = ws + OFF_PRM + (ch >> 1) * 16;
        float T11 = pr2[5], T12 = pr2[6], T21 = pr2[7], T22 = pr2[8];
        float U11 = pr2[9], U12 = pr2[10], U21 = pr2[11], U22 = pr2[12];
        ulong64* base = base0 + ch;

        // pass A: fold 16 summaries into segment summary
        float s1 = 0.f, s2 = 0.f;
#pragma unroll
        for (int j = 0; j < 16; ++j) {
            float2 l = rd8(&base[(size_t)(seg * 16 + j) * 256]);
            float n1 = fmaf(T11, s1, fmaf(T12, s2, l.x));
            float n2 = fmaf(T21, s1, fmaf(T22, s2, l.y));
            s1 = n1; s2 = n2;
        }
        sums[chl][seg] = make_float2(s1, s2);
        __syncthreads();
        if (tid < 32) {                            // serial combine, 8 segments
            float e1 = 0.f, e2 = 0.f;
#pragma unroll
            for (int k = 0; k < 8; ++k) {
                float2 t = sums[tid][k];
                sums[tid][k] = make_float2(e1, e2);
                float n1 = fmaf(U11, e1, fmaf(U12, e2, t.x));
                float n2 = fmaf(U21, e1, fmaf(U22, e2, t.y));
                e1 = n1; e2 = n2;
            }
        }
        __syncthreads();
        // pass B: re-read, overwrite with exclusive prefixes
        float2 E = sums[chl][seg];
        float e1 = E.x, e2 = E.y;
#pragma unroll
        for (int j = 0; j < 16; ++j) {
            size_t idx = (size_t)(seg * 16 + j) * 256;
            float2 l = rd8(&base[idx]);
            *(float2*)&base[idx] = make_float2(e1, e2);   // read by k_fuse2
            float n1 = fmaf(T11, e1, fmaf(T12, e2, l.x));
            float n2 = fmaf(T21, e1, fmaf(T22, e2, l.y));
            e1 = n1; e2 = n2;
        }
        __syncthreads();        // sums reuse next cg
    }
}

// ---------------------------------------------------------------------------
// Fused 2: ys_t = v2_t + [M^{t+1} P]_2 (R7-proven) -> ysb -> GEMM2, then
// epilogue through an LDS transpose (fo aliases ysb): each thread owns a
// fixed 4-column slab -> float4 X loads / out stores (25 mem instrs vs 68).
// LDS = 33.8 KB -> 4 blk/CU.  grid = 1024 x 256
// ---------------------------------------------------------------------------
__global__ __launch_bounds__(256) void k_fuse2(const float* __restrict__ X,
                                               const float* __restrict__ Dv,
                                               float* __restrict__ ws,
                                               float* __restrict__ out)
{
    __shared__ __align__(16) char ysmem[64 * 264 * 2];          // ysb | fo alias
    unsigned short (*ysb)[264] = (unsigned short (*)[264])ysmem;
    float (*fo)[132] = (float (*)[132])ysmem;                   // 64*132*4 = same size

    int tid = threadIdx.x;
    int bc = blockIdx.x;
    int b = bc >> 7, c = bc & 127;
    size_t row0 = (size_t)b * LEN_ + (size_t)c * CT_;

    // ---- build ys tile: thread = (channel pair q, t-segment of 32) ----
    {
        int q = tid & 127;                         // channels 2q, 2q+1 (same p=q)
        int tseg = tid >> 7;                       // t in [tseg*32, tseg*32+32)
        float4 Cp = *(const float4*)(ws + OFF_SUM + ((size_t)bc * 256 + 2 * q) * 2);
        const unsigned short* V2b = (const unsigned short*)(ws + OFF_V2) +
                                    (size_t)bc * 16384;       // [16][256][4]
        const float2* MPW = (const float2*)(ws + OFF_MPW);
#pragma unroll
        for (int g = 0; g < 8; ++g) {
            int tq = tseg * 8 + g;
            u16x8 v = *(const u16x8*)(V2b + (size_t)tq * 1024 + 8 * q);
            const float2* MP = MPW + ((size_t)tq * 128 + q) * 4;
            float4 mA = *(const float4*)MP;        // M^{4tq+1}, M^{4tq+2}
            float4 mB = *(const float4*)(MP + 2);  // M^{4tq+3}, M^{4tq+4}
            int t0 = tq * 4;
            float y0, y1;
            y0 = fmaf(mA.x, Cp.x, fmaf(mA.y, Cp.y, bf2f(v[0])));
            y1 = fmaf(mA.x, Cp.z, fmaf(mA.y, Cp.w, bf2f(v[4])));
            *(ushort2*)&ysb[t0 + 0][2 * q] = make_ushort2(f2bf_fast(y0), f2bf_fast(y1));
            y0 = fmaf(mA.z, Cp.x, fmaf(mA.w, Cp.y, bf2f(v[1])));
            y1 = fmaf(mA.z, Cp.z, fmaf(mA.w, Cp.w, bf2f(v[5])));
            *(ushort2*)&ysb[t0 + 1][2 * q] = make_ushort2(f2bf_fast(y0), f2bf_fast(y1));
            y0 = fmaf(mB.x, Cp.x, fmaf(mB.y, Cp.y, bf2f(v[2])));
            y1 = fmaf(mB.x, Cp.z, fmaf(mB.y, Cp.w, bf2f(v[6])));
            *(ushort2*)&ysb[t0 + 2][2 * q] = make_ushort2(f2bf_fast(y0), f2bf_fast(y1));
            y0 = fmaf(mB.z, Cp.x, fmaf(mB.w, Cp.y, bf2f(v[3])));
            y1 = fmaf(mB.z, Cp.z, fmaf(mB.w, Cp.w, bf2f(v[7])));
            *(ushort2*)&ysb[t0 + 3][2 * q] = make_ushort2(f2bf_fast(y0), f2bf_fast(y1));
        }
    }
    __syncthreads();

    // ---- GEMM2 64x128x256: A = ys (LDS bf16), B-frags from global W2T ----
    int wv = tid >> 6, lane = tid & 63;
    int l15 = lane & 15, quad = lane >> 4;
    int mrow = (wv & 1) * 32, ncol = (wv >> 1) * 64;
    f32x4 a2[2][4] = {};
    const unsigned short* W2T = (const unsigned short*)(ws + OFF_W2T);
#pragma unroll
    for (int kk = 0; kk < 8; ++kk) {
        int k0 = kk * 32 + quad * 8;
        bf16x8 af[2], bg[4];
#pragma unroll
        for (int mi = 0; mi < 2; ++mi) af[mi] = *(const bf16x8*)&ysb[mrow + mi * 16 + l15][k0];
#pragma unroll
        for (int nj = 0; nj < 4; ++nj)
            bg[nj] = *(const bf16x8*)(W2T + (size_t)(ncol + nj * 16 + l15) * 256 + k0);
#pragma unroll
        for (int mi = 0; mi < 2; ++mi)
#pragma unroll
            for (int nj = 0; nj < 4; ++nj)
                a2[mi][nj] = __builtin_amdgcn_mfma_f32_16x16x32_bf16(af[mi], bg[nj], a2[mi][nj], 0, 0, 0);
    }
    __syncthreads();            // all ysb reads done; fo may overwrite

    // ---- scatter a2 into fo (f32), then vectorized epilogue ----
#pragma unroll
    for (int mi = 0; mi < 2; ++mi)
#pragma unroll
        for (int nj = 0; nj < 4; ++nj)
#pragma unroll
            for (int r = 0; r < 4; ++r)
                fo[mrow + mi * 16 + quad * 4 + r][ncol + nj * 16 + l15] = a2[mi][nj][r];
    __syncthreads();

    {
        int colq = tid & 31;                       // fixed 4-col slab
        int rbase = tid >> 5;                      // rows rbase + 8k
        float4 dv = *(const float4*)(Dv + colq * 4);
#pragma unroll
        for (int k = 0; k < 8; ++k) {
            int row = rbase + 8 * k;
            float4 v = *(const float4*)&fo[row][colq * 4];
            const float* xp = X + (row0 + row) * 128 + colq * 4;
            float4 xv = *(const float4*)xp;
            float4 o;
            o.x = fmaf(dv.x, xv.x, v.x);
            o.y = fmaf(dv.y, xv.y, v.y);
            o.z = fmaf(dv.z, xv.z, v.z);
            o.w = fmaf(dv.w, xv.w, v.w);
            *(float4*)(out + (row0 + row) * 128 + colq * 4) = o;
        }
    }
}

// ---------------------------------------------------------------------------
extern "C" void kernel_launch(void* const* d_in, const int* in_sizes, int n_in,
                              void* d_out, int out_size, void* d_ws, size_t ws_size,
                              hipStream_t stream) {
    const float* x      = (const float*)d_in[0];
    const float* A_diag = (const float*)d_in[1];
    const float* G_diag = (const float*)d_in[2];
    const float* dt     = (const float*)d_in[3];
    const float* B      = (const float*)d_in[4];
    const float* C      = (const float*)d_in[5];
    const float* Dv     = (const float*)d_in[6];
    float* out = (float*)d_out;
    float* ws  = (float*)d_ws;

    k_setup<<<128, 256, 0, stream>>>(A_diag, G_diag, dt, B, C, ws);
    k_fuse1<<<BSZ_ * NC_, 256, 0, stream>>>(x, ws);
    k_fuse2<<<BSZ_ * NC_, 256, 0, stream>>>(x, Dv, ws, out);
}

// Round 11
// 132.777 us; speedup vs baseline: 3.2631x; 2.1081x over previous
//
#include <hip/hip_runtime.h>
#include <math.h>

// Problem dims
#define BSZ_ 8
#define LEN_ 8192
#define NC_  128          // scan chunks per sequence
#define CT_  64           // chunk length

typedef __attribute__((ext_vector_type(8))) short bf16x8;
typedef __attribute__((ext_vector_type(4))) float f32x4;
typedef __attribute__((ext_vector_type(4))) unsigned short u16x4;
typedef __attribute__((ext_vector_type(8))) unsigned short u16x8;

// Workspace layout (float offsets).
#define OFF_PRM 0                                   // 128*16 per-p scalars
#define OFF_W1T 2048                                // bf16 [256][128]  (W1^T: [pc][h])
#define OFF_W2T (OFF_W1T + 16384)                   // bf16 [128][256]  (W2^T: [h][pc])
#define OFF_MPW (OFF_W2T + 16384)                   // float2 [16][128][4]: (m21,m22) of M^{4tq+j+1}
#define OFF_SUM (OFF_MPW + 16384)                   // f32 chunk summaries/prefixes [8][128][256][2]
#define OFF_V2  (OFF_SUM + 524288)                  // ushort [bc][16][256][4]: v2 bf16, 4-t packed

__device__ __forceinline__ unsigned short f2bf(float f) {
    unsigned u = __builtin_bit_cast(unsigned, f);
    u += 0x7fffu + ((u >> 16) & 1u);               // round-to-nearest-even
    return (unsigned short)(u >> 16);
}

// cheap round-half-up bf16 (differs from RNE only on exact ties): 2 VALU ops
__device__ __forceinline__ unsigned short f2bf_fast(float f) {
    unsigned u = __builtin_bit_cast(unsigned, f);
    return (unsigned short)((u + 0x8000u) >> 16);
}

__device__ __forceinline__ float bf2f(unsigned short u) {
    return __builtin_bit_cast(float, (unsigned)u << 16);
}

// ---------------------------------------------------------------------------
// Setup: weight conversion + per-p scalars + packed M-power table + T=M^64,
// U=M^1024 for the parallel scan2.  grid = 128 x 256   (R7-verbatim)
// ---------------------------------------------------------------------------
__global__ __launch_bounds__(256) void k_setup(const float* __restrict__ A_diag,
                                               const float* __restrict__ G_diag,
                                               const float* __restrict__ dt,
                                               const float* __restrict__ B,
                                               const float* __restrict__ C,
                                               float* __restrict__ ws)
{
    int i = blockIdx.x * 256 + threadIdx.x;        // 0..32767
    // W1T[pc][h] = c1[p] * B[p,h,c]
    {
        int pc = i >> 7, h = i & 127;
        int p = pc >> 1, cc = pc & 1;
        float dts = 1.f / (1.f + expf(-dt[p]));
        float G = fmaxf(G_diag[p], 0.f);
        float c1 = dts / (1.f + dts * G);
        ((unsigned short*)(ws + OFF_W1T))[i] = f2bf(c1 * B[p * 256 + h * 2 + cc]);
    }
    // W2T[h][pc] = +Cr / -Ci ; C layout is exactly linear in i
    {
        float v = C[i];
        ((unsigned short*)(ws + OFF_W2T))[i] = f2bf((i & 1) ? -v : v);
    }
    // M-power table, fully parallel: threads 0..8191 -> (k = 1..64, p = 0..127)
    if (i < 8192) {
        int k = (i >> 7) + 1;                      // 1..64
        int p = i & 127;
        float dtv = dt[p];
        float dts = 1.f / (1.f + expf(-dtv));
        float A   = fmaxf(A_diag[p], 0.f);
        float G   = fmaxf(G_diag[p], 0.f);
        float dt2 = fmaxf(dts * dts, 1e-6f);
        float s   = sqrtf(1.f + dts * G);
        float A_low  = (2.f + dts * G - 2.f * s) / dt2;
        float A_high = (2.f + dts * G + 2.f * s) / dt2;
        float Af = A_low + fmaxf(A - A_low, 0.f) - fmaxf(A - A_high, 0.f);
        float S   = 1.f + dts * G;
        float M11 = 1.f / S;
        float M12 = -(dts / S) * Af;
        float M21 = dts / S;
        float M22 = 1.f - (dts * dts / S) * Af;

        // R = M^k via binary exponentiation (powers of M commute)
        float r11 = 1.f, r12 = 0.f, r21 = 0.f, r22 = 1.f;
        float b11 = M11, b12 = M12, b21 = M21, b22 = M22;
        int kk = k;
#pragma unroll
        for (int it = 0; it < 7; ++it) {
            if (kk & 1) {
                float t11 = b11 * r11 + b12 * r21;
                float t12 = b11 * r12 + b12 * r22;
                float t21 = b21 * r11 + b22 * r21;
                float t22 = b21 * r12 + b22 * r22;
                r11 = t11; r12 = t12; r21 = t21; r22 = t22;
            }
            float s11 = b11 * b11 + b12 * b21;
            float s12 = b11 * b12 + b12 * b22;
            float s21 = b21 * b11 + b22 * b21;
            float s22 = b21 * b12 + b22 * b22;
            b11 = s11; b12 = s12; b21 = s21; b22 = s22;
            kk >>= 1;
        }
        // packed table: MPW[tq][p][j] = (m21,m22) of M^{4tq+j+1}
        {
            int tq = (k - 1) >> 2, j = (k - 1) & 3;
            ((float2*)(ws + OFF_MPW))[((size_t)tq * 128 + p) * 4 + j] =
                make_float2(r21, r22);
        }

        float* prm = ws + OFF_PRM + p * 16;
        if (k == 1) {
            prm[0] = M11; prm[1] = M12; prm[2] = M21; prm[3] = M22; prm[4] = dts;
        }
        if (k == 64) {                              // T = M^64 for scan2
            prm[5] = r11; prm[6] = r12; prm[7] = r21; prm[8] = r22;
            // U = T^16 = M^1024 (segment step): 4 more squarings
            float u11 = r11, u12 = r12, u21 = r21, u22 = r22;
#pragma unroll
            for (int it = 0; it < 4; ++it) {
                float s11 = u11 * u11 + u12 * u21;
                float s12 = u11 * u12 + u12 * u22;
                float s21 = u21 * u11 + u22 * u21;
                float s22 = u21 * u12 + u22 * u22;
                u11 = s11; u12 = s12; u21 = s21; u22 = s22;
            }
            prm[9] = u11; prm[10] = u12; prm[11] = u21; prm[12] = u22;
        }
    }
}

// ---------------------------------------------------------------------------
// Shared device pieces
// ---------------------------------------------------------------------------
// stage 64 rows of X as bf16 into xs; one u16x8 (16B) LDS store per 8 values
__device__ __forceinline__ void stage_x(const float* __restrict__ X, size_t row0,
                                        int tid, unsigned short (*xs)[136])
{
    int r = tid >> 4, cl = (tid & 15) * 8;
#pragma unroll
    for (int i = 0; i < 4; ++i) {
        int rr = r + i * 16;
        const float* src = X + (row0 + rr) * 128 + cl;
        float4 v0 = *(const float4*)src;
        float4 v1 = *(const float4*)(src + 4);
        u16x8 pk;
        pk[0] = f2bf_fast(v0.x); pk[1] = f2bf_fast(v0.y);
        pk[2] = f2bf_fast(v0.z); pk[3] = f2bf_fast(v0.w);
        pk[4] = f2bf_fast(v1.x); pk[5] = f2bf_fast(v1.y);
        pk[6] = f2bf_fast(v1.z); pk[7] = f2bf_fast(v1.w);
        *(u16x8*)&xs[rr][cl] = pk;                 // one ds_write_b128
    }
}

// GEMM1 64x256x128: A = xs (LDS), B-frags straight from global W1T (L2-hot)
__device__ __forceinline__ void gemm1_acc(const unsigned short (*xs)[136],
                                          const unsigned short* __restrict__ W1T,
                                          int wv, int lane, f32x4 acc[4][4])
{
    int l15 = lane & 15, quad = lane >> 4;
    int nbase = wv * 64;
#pragma unroll
    for (int kk = 0; kk < 4; ++kk) {
        int k0 = kk * 32 + quad * 8;
        bf16x8 af[4], bg[4];
#pragma unroll
        for (int mi = 0; mi < 4; ++mi) af[mi] = *(const bf16x8*)&xs[mi * 16 + l15][k0];
#pragma unroll
        for (int nj = 0; nj < 4; ++nj)
            bg[nj] = *(const bf16x8*)(W1T + (size_t)(nbase + nj * 16 + l15) * 128 + k0);
#pragma unroll
        for (int mi = 0; mi < 4; ++mi)
#pragma unroll
            for (int nj = 0; nj < 4; ++nj)
                acc[mi][nj] = __builtin_amdgcn_mfma_f32_16x16x32_bf16(af[mi], bg[nj], acc[mi][nj], 0, 0, 0);
    }
}

// ---------------------------------------------------------------------------
// Fused 1 (R7-verbatim + vectorized stage_x): GEMM1 + chunk-local scan in
// TWO 32-row halves through fl aliased over xs.  n2 = h2 + dts*n1.
// v2 bf16 packed 4-t per lane (8B stores).  LDS 33.3 KB.  grid = 1024 x 256
// ---------------------------------------------------------------------------
__global__ __launch_bounds__(256) void k_fuse1(const float* __restrict__ X,
                                               float* __restrict__ ws)
{
    __shared__ __align__(16) char smem[32 * 260 * 4];
    unsigned short (*xs)[136] = (unsigned short (*)[136])smem;  // alias (dead after GEMM1)
    float (*fl)[260] = (float (*)[260])smem;                    // fp32 half-tile (32 rows)

    int tid = threadIdx.x;
    int bc = blockIdx.x;
    int b = bc >> 7, c = bc & 127;
    size_t row0 = (size_t)b * LEN_ + (size_t)c * CT_;

    stage_x(X, row0, tid, xs);
    __syncthreads();

    int wv = tid >> 6, lane = tid & 63;
    int l15 = lane & 15, quad = lane >> 4, nbase = wv * 64;
    f32x4 acc[4][4] = {};
    gemm1_acc(xs, (const unsigned short*)(ws + OFF_W1T), wv, lane, acc);
    __syncthreads();            // xs fully consumed; fl may now overwrite it

    const float* prm = ws + OFF_PRM + (tid >> 1) * 16;
    float M11 = prm[0], M12 = prm[1], dts = prm[4];
    u16x4* V2q = (u16x4*)(ws + OFF_V2) + (size_t)bc * 4096;  // [16][256] u16x4
    float h1 = 0.f, h2 = 0.f;

#pragma unroll
    for (int half = 0; half < 2; ++half) {
        // stage rows [half*32, half*32+32) of acc into fl
#pragma unroll
        for (int mi = 0; mi < 2; ++mi)
#pragma unroll
            for (int nj = 0; nj < 4; ++nj)
#pragma unroll
                for (int r = 0; r < 4; ++r)
                    fl[mi * 16 + quad * 4 + r][nbase + nj * 16 + l15] =
                        acc[half * 2 + mi][nj][r];
        __syncthreads();
        // scan 32 rows = 8 groups of 4; pack 4 bf16 -> one 8B store
#pragma unroll
        for (int g = 0; g < 8; ++g) {
            u16x4 pk;
#pragma unroll
            for (int i = 0; i < 4; ++i) {
                float u = fl[g * 4 + i][tid];
                float n1 = fmaf(M11, h1, fmaf(M12, h2, u));
                float n2 = fmaf(dts, n1, h2);      // == M21*h1 + M22*h2 + dts*u
                h1 = n1; h2 = n2;
                pk[i] = f2bf_fast(h2);
            }
            V2q[(half * 8 + g) * 256 + tid] = pk;
        }
        __syncthreads();        // fl reads done before next half overwrites
    }
    *(float2*)(ws + OFF_SUM + ((size_t)bc * 256 + tid) * 2) = make_float2(h1, h2);
}

// ---------------------------------------------------------------------------
// Pass 2 (R7-verbatim): two-level parallel combine, coalesced mapping.
// Serial depth 16+8+16.  grid = 64 x 256
// ---------------------------------------------------------------------------
__global__ __launch_bounds__(256) void k_scan2(float* __restrict__ ws)
{
    __shared__ float2 sums[32][8];
    int blk = blockIdx.x;
    int b = blk >> 3, chb = (blk & 7) * 32;
    int tid = threadIdx.x;
    int chl = tid & 31, seg = tid >> 5;            // ch fastest -> coalesced
    int ch = chb + chl;
    const float* prm = ws + OFF_PRM + (ch >> 1) * 16;
    float T11 = prm[5], T12 = prm[6], T21 = prm[7], T22 = prm[8];
    float U11 = prm[9], U12 = prm[10], U21 = prm[11], U22 = prm[12];
    float* base = ws + OFF_SUM + (size_t)b * 65536 + ch * 2;

    // pass A: load 16 summaries into regs, fold into segment summary
    float l1[16], l2[16];
    float s1 = 0.f, s2 = 0.f;
#pragma unroll
    for (int j = 0; j < 16; ++j) {
        float2 l = *(const float2*)(base + (size_t)(seg * 16 + j) * 512);
        l1[j] = l.x; l2[j] = l.y;
        float n1 = fmaf(T11, s1, fmaf(T12, s2, l.x));
        float n2 = fmaf(T21, s1, fmaf(T22, s2, l.y));
        s1 = n1; s2 = n2;
    }
    sums[chl][seg] = make_float2(s1, s2);
    __syncthreads();

    // serial combine across 8 segments (one lane per channel)
    if (tid < 32) {
        float e1 = 0.f, e2 = 0.f;
#pragma unroll
        for (int k = 0; k < 8; ++k) {
            float2 t = sums[tid][k];
            sums[tid][k] = make_float2(e1, e2);    // exclusive segment start
            float n1 = fmaf(U11, e1, fmaf(U12, e2, t.x));
            float n2 = fmaf(U21, e1, fmaf(U22, e2, t.y));
            e1 = n1; e2 = n2;
        }
    }
    __syncthreads();

    // pass B: replay 16 chunks writing exclusive prefixes
    float2 E = sums[chl][seg];
    float e1 = E.x, e2 = E.y;
#pragma unroll
    for (int j = 0; j < 16; ++j) {
        *(float2*)(base + (size_t)(seg * 16 + j) * 512) = make_float2(e1, e2);
        float n1 = fmaf(T11, e1, fmaf(T12, e2, l1[j]));
        float n2 = fmaf(T21, e1, fmaf(T22, e2, l2[j]));
        e1 = n1; e2 = n2;
    }
}

// ---------------------------------------------------------------------------
// Fused 2 (R7 build/GEMM2 + R10-verified fo-transpose epilogue):
// ys_t = v2_t + [M^{t+1} P]_2 -> ysb -> GEMM2 -> a2 through fo (f32 LDS,
// aliases ysb) -> float4 X/out epilogue (25 wide mem instrs vs 68 scalar).
// LDS = 33.8 KB -> 4 blk/CU.  grid = 1024 x 256
// ---------------------------------------------------------------------------
__global__ __launch_bounds__(256) void k_fuse2(const float* __restrict__ X,
                                               const float* __restrict__ Dv,
                                               float* __restrict__ ws,
                                               float* __restrict__ out)
{
    __shared__ __align__(16) char ysmem[64 * 264 * 2];          // ysb | fo alias
    unsigned short (*ysb)[264] = (unsigned short (*)[264])ysmem;
    float (*fo)[132] = (float (*)[132])ysmem;                   // 64*132*4 = same size

    int tid = threadIdx.x;
    int bc = blockIdx.x;
    int b = bc >> 7, c = bc & 127;
    size_t row0 = (size_t)b * LEN_ + (size_t)c * CT_;

    // ---- build ys tile: thread = (channel pair q, t-segment of 32) ----
    {
        int q = tid & 127;                         // channels 2q, 2q+1 (same p=q)
        int tseg = tid >> 7;                       // t in [tseg*32, tseg*32+32)
        float4 Cp = *(const float4*)(ws + OFF_SUM + ((size_t)bc * 256 + 2 * q) * 2);
        const unsigned short* V2b = (const unsigned short*)(ws + OFF_V2) +
                                    (size_t)bc * 16384;       // [16][256][4]
        const float2* MPW = (const float2*)(ws + OFF_MPW);
#pragma unroll
        for (int g = 0; g < 8; ++g) {
            int tq = tseg * 8 + g;
            u16x8 v = *(const u16x8*)(V2b + (size_t)tq * 1024 + 8 * q);
            const float2* MP = MPW + ((size_t)tq * 128 + q) * 4;
            float4 mA = *(const float4*)MP;        // M^{4tq+1}, M^{4tq+2}
            float4 mB = *(const float4*)(MP + 2);  // M^{4tq+3}, M^{4tq+4}
            int t0 = tq * 4;
            float y0, y1;
            y0 = fmaf(mA.x, Cp.x, fmaf(mA.y, Cp.y, bf2f(v[0])));
            y1 = fmaf(mA.x, Cp.z, fmaf(mA.y, Cp.w, bf2f(v[4])));
            *(ushort2*)&ysb[t0 + 0][2 * q] = make_ushort2(f2bf_fast(y0), f2bf_fast(y1));
            y0 = fmaf(mA.z, Cp.x, fmaf(mA.w, Cp.y, bf2f(v[1])));
            y1 = fmaf(mA.z, Cp.z, fmaf(mA.w, Cp.w, bf2f(v[5])));
            *(ushort2*)&ysb[t0 + 1][2 * q] = make_ushort2(f2bf_fast(y0), f2bf_fast(y1));
            y0 = fmaf(mB.x, Cp.x, fmaf(mB.y, Cp.y, bf2f(v[2])));
            y1 = fmaf(mB.x, Cp.z, fmaf(mB.y, Cp.w, bf2f(v[6])));
            *(ushort2*)&ysb[t0 + 2][2 * q] = make_ushort2(f2bf_fast(y0), f2bf_fast(y1));
            y0 = fmaf(mB.z, Cp.x, fmaf(mB.w, Cp.y, bf2f(v[3])));
            y1 = fmaf(mB.z, Cp.z, fmaf(mB.w, Cp.w, bf2f(v[7])));
            *(ushort2*)&ysb[t0 + 3][2 * q] = make_ushort2(f2bf_fast(y0), f2bf_fast(y1));
        }
    }
    __syncthreads();

    // ---- GEMM2 64x128x256: A = ys (LDS bf16), B-frags from global W2T ----
    int wv = tid >> 6, lane = tid & 63;
    int l15 = lane & 15, quad = lane >> 4;
    int mrow = (wv & 1) * 32, ncol = (wv >> 1) * 64;
    f32x4 a2[2][4] = {};
    const unsigned short* W2T = (const unsigned short*)(ws + OFF_W2T);
#pragma unroll
    for (int kk = 0; kk < 8; ++kk) {
        int k0 = kk * 32 + quad * 8;
        bf16x8 af[2], bg[4];
#pragma unroll
        for (int mi = 0; mi < 2; ++mi) af[mi] = *(const bf16x8*)&ysb[mrow + mi * 16 + l15][k0];
#pragma unroll
        for (int nj = 0; nj < 4; ++nj)
            bg[nj] = *(const bf16x8*)(W2T + (size_t)(ncol + nj * 16 + l15) * 256 + k0);
#pragma unroll
        for (int mi = 0; mi < 2; ++mi)
#pragma unroll
            for (int nj = 0; nj < 4; ++nj)
                a2[mi][nj] = __builtin_amdgcn_mfma_f32_16x16x32_bf16(af[mi], bg[nj], a2[mi][nj], 0, 0, 0);
    }
    __syncthreads();            // all ysb reads done; fo may overwrite

    // ---- scatter a2 into fo (f32), then vectorized float4 epilogue ----
#pragma unroll
    for (int mi = 0; mi < 2; ++mi)
#pragma unroll
        for (int nj = 0; nj < 4; ++nj)
#pragma unroll
            for (int r = 0; r < 4; ++r)
                fo[mrow + mi * 16 + quad * 4 + r][ncol + nj * 16 + l15] = a2[mi][nj][r];
    __syncthreads();

    {
        int colq = tid & 31;                       // fixed 4-col slab
        int rbase = tid >> 5;                      // rows rbase + 8k
        float4 dv = *(const float4*)(Dv + colq * 4);
#pragma unroll
        for (int k = 0; k < 8; ++k) {
            int row = rbase + 8 * k;
            float4 v = *(const float4*)&fo[row][colq * 4];
            const float* xp = X + (row0 + row) * 128 + colq * 4;
            float4 xv = *(const float4*)xp;
            float4 o;
            o.x = fmaf(dv.x, xv.x, v.x);
            o.y = fmaf(dv.y, xv.y, v.y);
            o.z = fmaf(dv.z, xv.z, v.z);
            o.w = fmaf(dv.w, xv.w, v.w);
            *(float4*)(out + (row0 + row) * 128 + colq * 4) = o;
        }
    }
}

// ---------------------------------------------------------------------------
extern "C" void kernel_launch(void* const* d_in, const int* in_sizes, int n_in,
                              void* d_out, int out_size, void* d_ws, size_t ws_size,
                              hipStream_t stream) {
    const float* x      = (const float*)d_in[0];
    const float* A_diag = (const float*)d_in[1];
    const float* G_diag = (const float*)d_in[2];
    const float* dt     = (const float*)d_in[3];
    const float* B      = (const float*)d_in[4];
    const float* C      = (const float*)d_in[5];
    const float* Dv     = (const float*)d_in[6];
    float* out = (float*)d_out;
    float* ws  = (float*)d_ws;

    k_setup<<<128, 256, 0, stream>>>(A_diag, G_diag, dt, B, C, ws);
    k_fuse1<<<BSZ_ * NC_, 256, 0, stream>>>(x, ws);
    k_scan2<<<64, 256, 0, stream>>>(ws);
    k_fuse2<<<BSZ_ * NC_, 256, 0, stream>>>(x, Dv, ws, out);
}